// Round 11
// baseline (250.753 us; speedup 1.0000x reference)
//
#include <hip/hip_runtime.h>

#define H 512
#define W 512
#define NW 4               // waves per block
#define SLOTS 3            // wave-private ring slots (1 target row each)

// Full-wave (64-lane) sum using DPP only — pure VALU. Result in lane 63.
__device__ __forceinline__ float wave_sum_dpp(float x) {
#define DPP_STEP(ctrl)                                                          \
    x += __int_as_float(__builtin_amdgcn_update_dpp(                            \
        0, __float_as_int(x), (ctrl), 0xF, 0xF, true))
    DPP_STEP(0x111);   // row_shr:1
    DPP_STEP(0x112);   // row_shr:2
    DPP_STEP(0x114);   // row_shr:4
    DPP_STEP(0x118);   // row_shr:8
    DPP_STEP(0x142);   // row_bcast:15
    DPP_STEP(0x143);   // row_bcast:31
#undef DPP_STEP
    return x;
}

__device__ __forceinline__ float4 ld4(const float* p) {
    return *reinterpret_cast<const float4*>(p);
}
__device__ __forceinline__ float2 ld2(const float* p) {
    return *reinterpret_cast<const float2*>(p);
}

// Async global->LDS DMA, 16 B/lane, linear dest (base + lane*16).
__device__ __forceinline__ void gl_lds16(const float* g, float* l) {
    __builtin_amdgcn_global_load_lds(
        (const __attribute__((address_space(1))) void*)g,
        (__attribute__((address_space(3))) void*)l,
        16, 0, 0);
}

// Counted vmcnt wait; sched_barrier(0) per rule #18.
#define WAITV(n) do { asm volatile("s_waitcnt vmcnt(" #n ")" ::: "memory");     \
                      __builtin_amdgcn_sched_barrier(0); } while (0)

// Fused kernel: per-wave 3-slot DMA ring (high occupancy: 24.6 KB LDS -> 6
// blocks/CU = 24 waves/CU), last-block final reduction (saves 2 launches).
__global__ __launch_bounds__(256, 8)
void dice_fused(const float* __restrict__ in, const float* __restrict__ tg,
                float* __restrict__ ws, unsigned* __restrict__ cnt,
                float* __restrict__ outp, int nblocks) {
    __shared__ __align__(16) float ring[NW][SLOTS][W];   // 24 KB
    __shared__ float warr[NW][32];
    __shared__ float sred[8][32];
    __shared__ unsigned lastrank;

    const int tid  = threadIdx.x;
    const int wave = tid >> 6, lane = tid & 63;

    const int bid = blockIdx.x;
    const int wrk = (bid & 7) * (nblocks >> 3) + (bid >> 3);   // XCD chunking

    const int q  = wrk * 4 + wave;     // global row-quad id
    const int b  = q >> 7;             // image (128 quads per image)
    const int y0 = (q & 127) << 2;     // first of 4 owned rows (<= 508)
    const float* __restrict__ inb = in + (size_t)b * (H * W);
    const float* __restrict__ tgb = tg + (size_t)b * (H * W);

    const int c0 = lane * 8;           // my 8 columns

    // ---- issue 8 input loads (oldest in the vmcnt FIFO) ----
    float4 ia[4], ic[4];
#pragma unroll
    for (int yi = 0; yi < 4; ++yi) {
        const float* rp = inb + (size_t)(y0 + yi) * W;
        ia[yi] = ld4(rp + c0);
        ic[yi] = ld4(rp + c0 + 4);
    }

    // ---- issue DMA for target rows 0,1 (2 events each) ----
#define TISSUE(t, slot) {                                                       \
        asm volatile("s_waitcnt lgkmcnt(0)" ::: "memory");                      \
        const float* rp = tgb + (size_t)((y0 - 2 + (t)) & (H - 1)) * W;         \
        gl_lds16(rp + lane * 4,       &ring[wave][slot][0]);                    \
        gl_lds16(rp + 256 + lane * 4, &ring[wave][slot][256]); }
    TISSUE(0, 0)
    TISSUE(1, 1)

    // ---- counted wait: 12 outstanding, <=4 means exactly the inputs landed ----
    WAITV(4);
    float iv[4][8];
    float isum = 0.f;
#pragma unroll
    for (int yi = 0; yi < 4; ++yi) {
        iv[yi][0] = ia[yi].x; iv[yi][1] = ia[yi].y;
        iv[yi][2] = ia[yi].z; iv[yi][3] = ia[yi].w;
        iv[yi][4] = ic[yi].x; iv[yi][5] = ic[yi].y;
        iv[yi][6] = ic[yi].z; iv[yi][7] = ic[yi].w;
#pragma unroll
        for (int j = 0; j < 8; ++j) isum += iv[yi][j];
    }
    isum = wave_sum_dpp(isum);
    if (lane == 63) warr[wave][25] = isum;

    float acc[25];
#pragma unroll
    for (int k = 0; k < 25; ++k) acc[k] = 0.f;
    float tsum = 0.f;

    // ---- steady pipeline: issue t+2, wait row t (FIFO-exact), consume ----
#define CONSUME(t) {                                                            \
        const float* rowp = &ring[wave][(t) % 3][0];                            \
        float tw[12];                                                           \
        const float4 a  = ld4(rowp + c0);                                       \
        const float4 cc = ld4(rowp + c0 + 4);                                   \
        const float2 lf = ld2(rowp + ((c0 - 2) & (W - 1)));                     \
        const float2 rg = ld2(rowp + ((c0 + 8) & (W - 1)));                     \
        tw[0]  = lf.x; tw[1]  = lf.y;                                           \
        tw[2]  = a.x;  tw[3]  = a.y;  tw[4] = a.z;  tw[5] = a.w;                \
        tw[6]  = cc.x; tw[7]  = cc.y; tw[8] = cc.z; tw[9] = cc.w;               \
        tw[10] = rg.x; tw[11] = rg.y;                                           \
        if ((t) >= 2 && (t) <= 5) {                                             \
            _Pragma("unroll")                                                   \
            for (int j = 0; j < 8; ++j) tsum += tw[j + 2];                      \
        }                                                                       \
        _Pragma("unroll")                                                       \
        for (int yi = 0; yi < 4; ++yi) {                                        \
            const int sy = yi + 2 - (t);                                        \
            if (sy < -2 || sy > 2) continue;                                    \
            _Pragma("unroll")                                                   \
            for (int sx = -2; sx <= 2; ++sx) {                                  \
                _Pragma("unroll")                                               \
                for (int j = 0; j < 8; ++j)                                     \
                    acc[(sy + 2) * 5 + (sx + 2)] += iv[yi][j] * tw[j + 2 - sx]; \
            }                                                                   \
        }                                                                       \
    }

    TISSUE(2, 2)  WAITV(4);  CONSUME(0)
    TISSUE(3, 0)  WAITV(4);  CONSUME(1)
    TISSUE(4, 1)  WAITV(4);  CONSUME(2)
    TISSUE(5, 2)  WAITV(4);  CONSUME(3)
    TISSUE(6, 0)  WAITV(4);  CONSUME(4)
    TISSUE(7, 1)  WAITV(4);  CONSUME(5)
    /* tail */    WAITV(2);  CONSUME(6)
                  WAITV(0);  CONSUME(7)
#undef CONSUME
#undef TISSUE

    // ---- per-wave DPP reduction ----
#pragma unroll
    for (int k = 0; k < 25; ++k) {
        const float v = wave_sum_dpp(acc[k]);
        if (lane == 63) warr[wave][k] = v;
    }
    {
        const float u = wave_sum_dpp(tsum);
        if (lane == 63) warr[wave][26] = u;
    }

    __syncthreads();
    if (tid < 27) {
        const float s = warr[0][tid] + warr[1][tid] + warr[2][tid] + warr[3][tid];
        ws[(size_t)bid * 32 + tid] = s;   // [block][k] layout: coalesced finale
    }

    // ---- last-block final reduction (fused tail; deterministic) ----
    __threadfence();   // release ws stores device-wide
    if (tid == 0)
        lastrank = __hip_atomic_fetch_add(cnt, 1u, __ATOMIC_ACQ_REL,
                                          __HIP_MEMORY_SCOPE_AGENT);
    __syncthreads();
    if (lastrank == (unsigned)(nblocks - 1)) {
        __threadfence();                  // acquire side for ws reads
        const int k = tid & 31, g = tid >> 5;   // 8 groups x 32 quantities
        float s = 0.f;
        for (int i = g; i < nblocks; i += 8)    // coalesced: 32 consecutive k
            s += ws[(size_t)i * 32 + k];
        sred[g][k] = s;
        __syncthreads();
        if (tid < 32) {
            float t2 = 0.f;
#pragma unroll
            for (int gg = 0; gg < 8; ++gg) t2 += sred[gg][tid];
            sred[0][tid] = t2;
        }
        __syncthreads();
        if (tid == 0) {
            float m = sred[0][0];
#pragma unroll
            for (int k2 = 1; k2 < 25; ++k2) m = fmaxf(m, sred[0][k2]);
            const float denom = sred[0][25] + sred[0][26] + 1.0f;  // i+t+SMOOTH
            outp[0] = 1.0f - (2.0f * m + 1.0f) / denom;  // min loss == max inter
        }
    }
}

extern "C" void kernel_launch(void* const* d_in, const int* in_sizes, int n_in,
                              void* d_out, int out_size, void* d_ws, size_t ws_size,
                              hipStream_t stream) {
    const float* inputs  = (const float*)d_in[0];
    const float* targets = (const float*)d_in[1];
    float* out = (float*)d_out;
    float* ws  = (float*)d_ws;

    const int B = in_sizes[0] / (H * W);    // 64
    const int nblocks = B * (H / 4) / 4;    // 2048 blocks x 4 waves x 4 rows

    unsigned* cnt = (unsigned*)(ws + (size_t)nblocks * 32);
    hipMemsetAsync(cnt, 0, sizeof(unsigned), stream);   // graph-capturable

    dice_fused<<<nblocks, 256, 0, stream>>>(inputs, targets, ws, cnt, out, nblocks);
}

// Round 12
// 146.782 us; speedup vs baseline: 1.7083x; 1.7083x over previous
//
#include <hip/hip_runtime.h>

#define H 512
#define W 512
#define SLAB 8              // input rows per slab
#define TROWS 12            // staged target rows (SLAB + 4 halo)
#define BROWS 20            // rows per buffer (12 target + 8 input)
#define NSLAB 8             // slabs per block (64 rows per block)

// Full-wave (64-lane) sum using DPP only — pure VALU. Result in lane 63.
__device__ __forceinline__ float wave_sum_dpp(float x) {
#define DPP_STEP(ctrl)                                                          \
    x += __int_as_float(__builtin_amdgcn_update_dpp(                            \
        0, __float_as_int(x), (ctrl), 0xF, 0xF, true))
    DPP_STEP(0x111);   // row_shr:1
    DPP_STEP(0x112);   // row_shr:2
    DPP_STEP(0x114);   // row_shr:4
    DPP_STEP(0x118);   // row_shr:8
    DPP_STEP(0x142);   // row_bcast:15
    DPP_STEP(0x143);   // row_bcast:31
#undef DPP_STEP
    return x;
}

__device__ __forceinline__ float4 ld4(const float* p) {
    return *reinterpret_cast<const float4*>(p);
}
__device__ __forceinline__ float2 ld2(const float* p) {
    return *reinterpret_cast<const float2*>(p);
}

// Async global->LDS DMA, 16 B/lane, linear dest (base + lane*16).
__device__ __forceinline__ void gl_lds16(const float* g, float* l) {
    __builtin_amdgcn_global_load_lds(
        (const __attribute__((address_space(1))) void*)g,
        (__attribute__((address_space(3))) void*)l,
        16, 0, 0);
}

// Kernel 1: 2-phase double-buffered slab pipeline (T3 minimum recipe).
// 512 blocks x 256 threads; block owns 64 consecutive rows of one image,
// processed as 8 slabs of 8 rows. Loop: issue DMA(slab s+1 -> buf[s+1&1]),
// compute slab s from buf[s&1], then ONE vmcnt-drain+barrier (inside
// __syncthreads) AFTER compute — the next tile's 40 KB rides out during the
// FMA work. Accumulators persist across slabs; one DPP reduction per block.
__global__ __launch_bounds__(256)
void dice_partial(const float* __restrict__ in, const float* __restrict__ tg,
                  float* __restrict__ ws, int nblocks) {
    __shared__ __align__(16) float buf[2][BROWS][W];   // 81920 B -> 2 blocks/CU

    const int tid  = threadIdx.x;
    const int wave = tid >> 6, lane = tid & 63;

    // Bijective XCD chunking (512 % 8 == 0); regions of one image stay together.
    const int bid = blockIdx.x;
    const int wrk = (bid & 7) * (nblocks >> 3) + (bid >> 3);

    const int b   = wrk >> 3;           // image (8 regions per image)
    const int r0  = (wrk & 7) * 64;     // region top row
    const float* __restrict__ inb = in + (size_t)b * (H * W);
    const float* __restrict__ tgb = tg + (size_t)b * (H * W);

    const int c0 = lane * 8;            // my 8 columns

    // Stage slab s into buffer sb: 12 target rows (y0-2..y0+9, wrapped) then
    // 8 input rows. 40 events of 1 KB; 10 per wave; dest wave-uniform.
#define STAGE(s, sb) {                                                          \
        const int y0s = r0 + (s) * SLAB;                                        \
        _Pragma("unroll")                                                       \
        for (int k = 0; k < 10; ++k) {                                          \
            const int e    = wave * 10 + k;                                     \
            const int rr   = e >> 1;                                            \
            const int half = (e & 1) * 256;                                     \
            const float* src = (rr < TROWS)                                     \
                ? tgb + (size_t)((y0s - 2 + rr) & (H - 1)) * W + half           \
                : inb + (size_t)(y0s + (rr - TROWS)) * W + half;                \
            gl_lds16(src + lane * 4, &buf[sb][rr][half]);                       \
        }                                                                       \
    }

    float acc[25];
#pragma unroll
    for (int k = 0; k < 25; ++k) acc[k] = 0.f;
    float isum = 0.f, tsum = 0.f;

    STAGE(0, 0)
    __syncthreads();                     // prologue fill (one-time exposure)

#pragma unroll
    for (int s = 0; s < NSLAB; ++s) {
        if (s + 1 < NSLAB) STAGE(s + 1, (s + 1) & 1)   // next tile in flight

        // ---- compute slab s from buf[s&1]; wave owns input rows 2w,2w+1 ----
        const int sb = s & 1;
        float iv[2][8];
#pragma unroll
        for (int yi = 0; yi < 2; ++yi) {
            const float* rowp = &buf[sb][TROWS + 2 * wave + yi][0];
            const float4 a  = ld4(rowp + c0);
            const float4 cc = ld4(rowp + c0 + 4);
            iv[yi][0] = a.x;  iv[yi][1] = a.y;  iv[yi][2] = a.z;  iv[yi][3] = a.w;
            iv[yi][4] = cc.x; iv[yi][5] = cc.y; iv[yi][6] = cc.z; iv[yi][7] = cc.w;
#pragma unroll
            for (int j = 0; j < 8; ++j) isum += iv[yi][j];
        }

        // target rows t = 0..5 -> staged row 2w+t (= global y0+2w-2+t)
#pragma unroll
        for (int t = 0; t < 6; ++t) {
            const float* rowp = &buf[sb][2 * wave + t][0];
            float tw[12];                  // tw[c] = target col c0 + c - 2
            const float4 a  = ld4(rowp + c0);
            const float4 cc = ld4(rowp + c0 + 4);
            const float2 lf = ld2(rowp + ((c0 - 2) & (W - 1)));
            const float2 rg = ld2(rowp + ((c0 + 8) & (W - 1)));
            tw[0]  = lf.x; tw[1]  = lf.y;
            tw[2]  = a.x;  tw[3]  = a.y;  tw[4] = a.z;  tw[5] = a.w;
            tw[6]  = cc.x; tw[7]  = cc.y; tw[8] = cc.z; tw[9] = cc.w;
            tw[10] = rg.x; tw[11] = rg.y;

            if (t == 2 || t == 3) {        // staged rows 2w+2,2w+3 = own rows
#pragma unroll
                for (int j = 0; j < 8; ++j) tsum += tw[j + 2];
            }

#pragma unroll
            for (int yi = 0; yi < 2; ++yi) {
                const int sy = yi + 2 - t; // in-row (2w+yi) vs tg-row (2w+t-2)
                if (sy < -2 || sy > 2) continue;   // 10 live pairs
#pragma unroll
                for (int sx = -2; sx <= 2; ++sx) {
#pragma unroll
                    for (int j = 0; j < 8; ++j)
                        acc[(sy + 2) * 5 + (sx + 2)] += iv[yi][j] * tw[j + 2 - sx];
                }
            }
        }

        __syncthreads();   // drains vmcnt AFTER compute: tile s+1 has landed
    }
#undef STAGE

    // ---- once per block: DPP-reduce 27 quantities (warr aliased onto buf) ----
    float* warrf = &buf[0][0][0];          // buffers dead; 4x32 floats reused
#pragma unroll
    for (int k = 0; k < 25; ++k) {
        const float v = wave_sum_dpp(acc[k]);
        if (lane == 63) warrf[wave * 32 + k] = v;
    }
    {
        const float v = wave_sum_dpp(isum);
        if (lane == 63) warrf[wave * 32 + 25] = v;
        const float u = wave_sum_dpp(tsum);
        if (lane == 63) warrf[wave * 32 + 26] = u;
    }

    __syncthreads();
    if (tid < 27) {
        const float s = warrf[tid] + warrf[32 + tid] + warrf[64 + tid] + warrf[96 + tid];
        ws[tid * nblocks + bid] = s;       // [k][block] for coalesced pass 2
    }
}

// Kernel 2: 27 blocks, block k tree-reduces the per-block partials for quantity k.
__global__ __launch_bounds__(256)
void dice_reduce(const float* __restrict__ ws, float* __restrict__ tot, int nblocks) {
    __shared__ float red[4];
    const int k = blockIdx.x;
    const int tid = threadIdx.x;
    const float* p = ws + (size_t)k * nblocks;

    float s = 0.f;
    for (int i = tid; i < nblocks; i += 256) s += p[i];
    s = wave_sum_dpp(s);
    if ((tid & 63) == 63) red[tid >> 6] = s;
    __syncthreads();
    if (tid == 0) tot[k] = red[0] + red[1] + red[2] + red[3];
}

// Kernel 3: one wave — 25-way max + final loss scalar.
__global__ void dice_out(const float* __restrict__ tot, float* __restrict__ out) {
    const int tid = threadIdx.x;   // blockDim = 64
    float v = (tid < 25) ? tot[tid] : -1e30f;
#pragma unroll
    for (int off = 32; off; off >>= 1) v = fmaxf(v, __shfl_down(v, off, 64));
    if (tid == 0) {
        const float denom = tot[25] + tot[26] + 1.0f;   // i_sum + t_sum + SMOOTH
        out[0] = 1.0f - (2.0f * v + 1.0f) / denom;      // min loss == max intersection
    }
}

extern "C" void kernel_launch(void* const* d_in, const int* in_sizes, int n_in,
                              void* d_out, int out_size, void* d_ws, size_t ws_size,
                              hipStream_t stream) {
    const float* inputs  = (const float*)d_in[0];
    const float* targets = (const float*)d_in[1];
    float* out = (float*)d_out;
    float* ws  = (float*)d_ws;

    const int B = in_sizes[0] / (H * W);      // 64
    const int nblocks = B * 8;                // 512 blocks, 64 rows each

    float* tot = ws + (size_t)27 * nblocks;   // 27 scalar totals after the table

    dice_partial<<<nblocks, 256, 0, stream>>>(inputs, targets, ws, nblocks);
    dice_reduce<<<27, 256, 0, stream>>>(ws, tot, nblocks);
    dice_out<<<1, 64, 0, stream>>>(tot, out);
}

// Round 13
// 49.453 us; speedup vs baseline: 5.0705x; 2.9681x over previous
//
#include <hip/hip_runtime.h>

#define H 512
#define W 512
#define TILE_W 64
#define TILE_H 128
#define TG_ROWS (TILE_H + 4)   // 132 staged target rows
#define TG_C4 18               // float4 chunks per staged row (72 cols: x0-4..x0+67)
#define TG_STRIDE 76           // padded row stride (R4-verified bank behavior)
#define NWAVE 8                // 512 threads

// Full-wave (64-lane) sum using DPP only — pure VALU. Result in lane 63.
__device__ __forceinline__ float wave_sum_dpp(float x) {
#define DPP_STEP(ctrl)                                                          \
    x += __int_as_float(__builtin_amdgcn_update_dpp(                            \
        0, __float_as_int(x), (ctrl), 0xF, 0xF, true))
    DPP_STEP(0x111);   // row_shr:1
    DPP_STEP(0x112);   // row_shr:2
    DPP_STEP(0x114);   // row_shr:4
    DPP_STEP(0x118);   // row_shr:8
    DPP_STEP(0x142);   // row_bcast:15
    DPP_STEP(0x143);   // row_bcast:31
#undef DPP_STEP
    return x;
}

__device__ __forceinline__ float4 ld4(const float* p) {
    return *reinterpret_cast<const float4*>(p);
}

// Kernel 1: R4's verified structure, occupancy-doubled. 128x64 tile, 512 thr,
// LDS 40128 B -> 4 blocks/CU = 32 waves/CU (R4 was 18). Same per-thread body
// as R4 (VGPR 36-class: acc[5] + in-loop DPP). warr eliminated: lane 63 writes
// wave-level sums straight to ws[27][nblocks*8].
__global__ __launch_bounds__(512, 8)
void dice_partial(const float* __restrict__ in, const float* __restrict__ tg,
                  float* __restrict__ ws, int nblocks) {
    __shared__ __align__(16) float tgs[TG_ROWS * TG_STRIDE];   // 40128 B

    const int tid  = threadIdx.x;
    const int wave = tid >> 6, lane = tid & 63;

    // Bijective XCD chunking (nblocks % 8 == 0); consecutive tiles share halo.
    const int bid = blockIdx.x;
    const int wrk = (bid & 7) * (nblocks >> 3) + (bid >> 3);

    const int b    = wrk >> 5;                 // image (32 tiles per image)
    const int tile = wrk & 31;
    const int y0   = (tile >> 3) * TILE_H;     // 4 vertical bands
    const int x0   = (tile & 7) * TILE_W;      // 8 horizontal tiles
    const size_t ibase = (size_t)b * (H * W);

    // ---- stage target tile: rows y0-2..y0+129, cols x0-4..x0+67 ----
    const int x40 = x0 >> 2;
#pragma unroll
    for (int ii = 0; ii < 5; ++ii) {
        const int idx = tid + ii * 512;
        if (idx < TG_ROWS * TG_C4) {
            const int rr = idx / TG_C4;
            const int c4 = idx - rr * TG_C4;
            const int gy  = (y0 - 2 + rr) & (H - 1);
            const int gx4 = (x40 - 1 + c4) & (W / 4 - 1);
            const float4 v = ld4(tg + ibase + (size_t)gy * W + (size_t)gx4 * 4);
            *reinterpret_cast<float4*>(&tgs[rr * TG_STRIDE + c4 * 4]) = v;
        }
    }

    // ---- this thread's 16 input pixels: row y0+r, cols x0+16*sseg.. ----
    const int r = tid >> 2;          // 0..127 tile row
    const int sseg = tid & 3;        // 0..3 segment
    const float* ip = in + ibase + (size_t)(y0 + r) * W + x0 + sseg * 16;
    float iv[16];
#pragma unroll
    for (int k = 0; k < 4; ++k) {
        const float4 v = ld4(ip + 4 * k);
        iv[4*k+0] = v.x; iv[4*k+1] = v.y; iv[4*k+2] = v.z; iv[4*k+3] = v.w;
    }
    float isum = 0.f;
#pragma unroll
    for (int k = 0; k < 16; ++k) isum += iv[k];

    __syncthreads();   // staging complete

    const int wb = bid * NWAVE + wave;     // this wave's output slot

    // ---- 25 shifted dot products; acc[5] live per t; DPP + store in-loop ----
    float tsum = 0.f;
#pragma unroll
    for (int t = 0; t < 5; ++t) {
        float wrow[24];
        const float* base = &tgs[(r + t) * TG_STRIDE + sseg * 16];
#pragma unroll
        for (int k = 0; k < 6; ++k) {
            const float4 v = ld4(base + 4 * k);
            wrow[4*k+0] = v.x; wrow[4*k+1] = v.y; wrow[4*k+2] = v.z; wrow[4*k+3] = v.w;
        }

        float acc[5];
#pragma unroll
        for (int ss = 0; ss < 5; ++ss) acc[ss] = 0.f;
#pragma unroll
        for (int ss = 0; ss < 5; ++ss) {
#pragma unroll
            for (int px = 0; px < 16; ++px)
                acc[ss] += iv[px] * wrow[px + 6 - ss];
        }

        if (t == 2) {   // center row: each target element counted exactly once
#pragma unroll
            for (int px = 0; px < 16; ++px) tsum += wrow[px + 4];
        }

#pragma unroll
        for (int ss = 0; ss < 5; ++ss) {
            const float v = wave_sum_dpp(acc[ss]);
            if (lane == 63) ws[(size_t)(t * 5 + ss) * (nblocks * NWAVE) + wb] = v;
        }
    }

    {
        const float v = wave_sum_dpp(isum);
        if (lane == 63) ws[(size_t)25 * (nblocks * NWAVE) + wb] = v;
        const float u = wave_sum_dpp(tsum);
        if (lane == 63) ws[(size_t)26 * (nblocks * NWAVE) + wb] = u;
    }
}

// Kernel 2: 27 blocks, block k tree-reduces the per-wave partials for quantity k.
__global__ __launch_bounds__(256)
void dice_reduce(const float* __restrict__ ws, float* __restrict__ tot, int nent) {
    __shared__ float red[4];
    const int k = blockIdx.x;
    const int tid = threadIdx.x;
    const float* p = ws + (size_t)k * nent;

    float s = 0.f;
    for (int i = tid; i < nent; i += 256) s += p[i];
    s = wave_sum_dpp(s);
    if ((tid & 63) == 63) red[tid >> 6] = s;
    __syncthreads();
    if (tid == 0) tot[k] = red[0] + red[1] + red[2] + red[3];
}

// Kernel 3: one wave — 25-way max + final loss scalar.
__global__ void dice_out(const float* __restrict__ tot, float* __restrict__ out) {
    const int tid = threadIdx.x;   // blockDim = 64
    float v = (tid < 25) ? tot[tid] : -1e30f;
#pragma unroll
    for (int off = 32; off; off >>= 1) v = fmaxf(v, __shfl_down(v, off, 64));
    if (tid == 0) {
        const float denom = tot[25] + tot[26] + 1.0f;   // i_sum + t_sum + SMOOTH
        out[0] = 1.0f - (2.0f * v + 1.0f) / denom;      // min loss == max intersection
    }
}

extern "C" void kernel_launch(void* const* d_in, const int* in_sizes, int n_in,
                              void* d_out, int out_size, void* d_ws, size_t ws_size,
                              hipStream_t stream) {
    const float* inputs  = (const float*)d_in[0];
    const float* targets = (const float*)d_in[1];
    float* out = (float*)d_out;
    float* ws  = (float*)d_ws;

    const int B = in_sizes[0] / (H * W);            // 64
    const int nblocks = B * 32;                     // 2048 tiles (128x64 each)
    const int nent = nblocks * NWAVE;               // 16384 per quantity

    float* tot = ws + (size_t)27 * nent;            // 27 totals after the table

    dice_partial<<<nblocks, 512, 0, stream>>>(inputs, targets, ws, nblocks);
    dice_reduce<<<27, 256, 0, stream>>>(ws, tot, nent);
    dice_out<<<1, 64, 0, stream>>>(tot, out);
}